// Round 2
// baseline (79.477 us; speedup 1.0000x reference)
//
#include <hip/hip_runtime.h>
#include <stdint.h>

typedef uint16_t u16;
typedef __attribute__((ext_vector_type(4))) float f32x4;
typedef __attribute__((ext_vector_type(8))) short short8;
typedef __attribute__((ext_vector_type(4))) float float4v;
typedef __attribute__((ext_vector_type(4))) uint16_t u16x4;
typedef __attribute__((ext_vector_type(8))) uint16_t u16x8;

#define DIMQ 1024
#define BATCH 8192
#define KDIM 1024
#define NDIM 1024

__device__ __forceinline__ u16 f2bf(float f) {
  uint32_t u = __float_as_uint(f);
  u += 0x7fffu + ((u >> 16) & 1u);
  return (u16)(u >> 16);
}

// complex 2x2 layout: {00r,00i, 01r,01i, 10r,10i, 11r,11i}
__device__ inline void cmul2x2(float* O, const float* A, const float* B) {
  for (int r = 0; r < 2; ++r)
    for (int c = 0; c < 2; ++c) {
      float re = 0.f, im = 0.f;
      for (int j = 0; j < 2; ++j) {
        float ar = A[(r*2+j)*2], ai = A[(r*2+j)*2+1];
        float br = B[(j*2+c)*2], bi = B[(j*2+c)*2+1];
        re += ar*br - ai*bi;
        im += ar*bi + ai*br;
      }
      O[(r*2+c)*2]   = re;
      O[(r*2+c)*2+1] = im;
    }
}
__device__ inline void mk_rx(float* m, float t) {
  float s, c; sincosf(0.5f*t, &s, &c);
  m[0]=c; m[1]=0; m[2]=0; m[3]=-s; m[4]=0; m[5]=-s; m[6]=c; m[7]=0;
}
__device__ inline void mk_ry(float* m, float t) {
  float s, c; sincosf(0.5f*t, &s, &c);
  m[0]=c; m[1]=0; m[2]=-s; m[3]=0; m[4]=s; m[5]=0; m[6]=c; m[7]=0;
}
__device__ inline void mk_rz(float* m, float t) {
  float s, c; sincosf(0.5f*t, &s, &c);
  m[0]=c; m[1]=-s; m[2]=0; m[3]=0; m[4]=0; m[5]=0; m[6]=c; m[7]=s;
}

// One WAVE per basis state d. State (1024 complex) lives in registers:
// lane L holds amps x = L*16 + r, r=0..15 (bit p of x: p<4 -> reg bit, p>=4 -> lane bit p-4).
// Adjoint circuit: stage 0 = adjoint of final RY/RZ/RY block; stages 1..4 = layers 3..0,
// each preceded by the adjoint CNOT-ring permutation (via per-wave LDS scratch).
// Fused-gate matrices computed in-block (threads 0..49).
__global__ __launch_bounds__(256) void build_M(const float* __restrict__ w,
                                               u16* __restrict__ Bmat) {
  __shared__ float gm[400];
  __shared__ float Lr[4][1024];
  __shared__ float Li[4][1024];
  int t = threadIdx.x;
  if (t < 50) {
    float A[8], B[8], C[8], T[8], O[8];
    if (t < 10) {
      mk_ry(A, -w[120 + t]);
      mk_rz(B, -w[130 + t]);
      mk_ry(C, -w[140 + t]);
    } else {
      int s = (t - 10) / 10, q = (t - 10) % 10, l = 3 - s;
      mk_rx(A, -w[l*30 + q]);
      mk_ry(B, -w[l*30 + 10 + q]);
      mk_rz(C, -w[l*30 + 20 + q]);
    }
    cmul2x2(T, A, B);
    cmul2x2(O, T, C);
#pragma unroll
    for (int j = 0; j < 8; ++j) gm[t*8 + j] = O[j];
  }
  __syncthreads();

  int wave = t >> 6, lane = t & 63;
  int d = blockIdx.x * 4 + wave;
  float ar[16], ai[16];
#pragma unroll
  for (int r = 0; r < 16; ++r) {
    ar[r] = ((lane*16 + r) == d) ? 1.0f : 0.0f;
    ai[r] = 0.0f;
  }

  for (int stage = 0; stage < 5; ++stage) {
    if (stage) {
      // adjoint CNOT-ring permutation: new[x] = old[sigma(x)]
#pragma unroll
      for (int g = 0; g < 4; ++g) {
        *(float4v*)&Lr[wave][lane*16 + g*4] =
            (float4v){ar[g*4], ar[g*4+1], ar[g*4+2], ar[g*4+3]};
        *(float4v*)&Li[wave][lane*16 + g*4] =
            (float4v){ai[g*4], ai[g*4+1], ai[g*4+2], ai[g*4+3]};
      }
      __syncthreads();
#pragma unroll
      for (int r = 0; r < 16; ++r) {
        int x = lane*16 + r;
        int y = x;
#pragma unroll
        for (int qq = 0; qq < 9; ++qq) y ^= ((y >> (9 - qq)) & 1) << (8 - qq);
        y ^= (y & 1) << 9;
        ar[r] = Lr[wave][y];
        ai[r] = Li[wave][y];
      }
      __syncthreads();
    }
    // gates q = 0..5: act on lane bits (p = 9-q >= 4)
#pragma unroll
    for (int q = 0; q < 6; ++q) {
      const int pb = 5 - q;  // lane bit
      const float* g = &gm[(stage*10 + q)*8];
      float u00r=g[0], u00i=g[1], u01r=g[2], u01i=g[3];
      float u10r=g[4], u10i=g[5], u11r=g[6], u11i=g[7];
      int bit = (lane >> pb) & 1;
      float cmr = bit ? u11r : u00r, cmi = bit ? u11i : u00i;
      float cor = bit ? u10r : u01r, coi = bit ? u10i : u01i;
#pragma unroll
      for (int r = 0; r < 16; ++r) {
        float otr = __shfl_xor(ar[r], 1 << pb, 64);
        float oti = __shfl_xor(ai[r], 1 << pb, 64);
        float nr = cmr*ar[r] - cmi*ai[r] + cor*otr - coi*oti;
        float ni = cmr*ai[r] + cmi*ar[r] + cor*oti + coi*otr;
        ar[r] = nr; ai[r] = ni;
      }
    }
    // gates q = 6..9: act on reg bits (p = 9-q in 3..0)
#pragma unroll
    for (int q = 6; q < 10; ++q) {
      const int p = 9 - q;
      const float* g = &gm[(stage*10 + q)*8];
      float u00r=g[0], u00i=g[1], u01r=g[2], u01i=g[3];
      float u10r=g[4], u10i=g[5], u11r=g[6], u11i=g[7];
#pragma unroll
      for (int h = 0; h < 8; ++h) {
        int r0 = ((h >> p) << (p+1)) | (h & ((1 << p) - 1));
        int r1 = r0 | (1 << p);
        float a0r = ar[r0], a0i = ai[r0], a1r = ar[r1], a1i = ai[r1];
        ar[r0] = u00r*a0r - u00i*a0i + u01r*a1r - u01i*a1i;
        ai[r0] = u00r*a0i + u00i*a0r + u01r*a1i + u01i*a1r;
        ar[r1] = u10r*a0r - u10i*a0i + u11r*a1r - u11i*a1i;
        ai[r1] = u10r*a0i + u10i*a0r + u11r*a1i + u11i*a1r;
      }
    }
  }

  // write row d of M = Re(U) as bf16; each lane writes 32 contiguous bytes
  u16x8 v0, v1;
#pragma unroll
  for (int r = 0; r < 8; ++r) v0[r] = f2bf(ar[r]);
#pragma unroll
  for (int r = 0; r < 8; ++r) v1[r] = f2bf(ar[8 + r]);
  u16* row = Bmat + (size_t)d * DIMQ + lane * 16;
  *(u16x8*)row = v0;
  *(u16x8*)(row + 8) = v1;
}

// Row-normalize x (fp32) -> bf16. One wave per row, 4 rows per block.
__global__ __launch_bounds__(256) void normalize_rows(const float* __restrict__ x,
                                                      u16* __restrict__ Abf) {
  int lane = threadIdx.x & 63, wave = threadIdx.x >> 6;
  int row = blockIdx.x * 4 + wave;
  const float* xr = x + (size_t)row * DIMQ;
  float4v v[4];
  float ss = 0.f;
#pragma unroll
  for (int j = 0; j < 4; ++j) {
    v[j] = *(const float4v*)(xr + j*256 + lane*4);
    ss += v[j][0]*v[j][0] + v[j][1]*v[j][1] + v[j][2]*v[j][2] + v[j][3]*v[j][3];
  }
#pragma unroll
  for (int off = 32; off; off >>= 1) ss += __shfl_xor(ss, off, 64);
  float inv = 1.0f / fmaxf(sqrtf(ss), 1e-12f);
  u16* orow = Abf + (size_t)row * DIMQ;
#pragma unroll
  for (int j = 0; j < 4; ++j) {
    u16x4 o;
#pragma unroll
    for (int e = 0; e < 4; ++e) o[e] = f2bf(v[j][e] * inv);
    *(u16x4*)(orow + j*256 + lane*4) = o;
  }
}

// C[8192,1024] = A[8192,1024] * B[1024,1024]^T   (bf16 in, fp32 out)
// 128x128 tile, BK=64, 4 waves (2x2 of 64x64), 16x16x32 bf16 MFMA,
// global_load_lds width-16 staging (m97 structure, halved barrier count).
__global__ __launch_bounds__(256) void gemm_bt(const u16* __restrict__ A,
                                               const u16* __restrict__ Bm,
                                               float* __restrict__ C) {
  __shared__ u16 As[128*64];
  __shared__ u16 Bs[128*64];
  int t = threadIdx.x, lane = t & 63, wave = t >> 6;
  // XCD-aware swizzle: nwg=512, 512%8==0 -> nid=(bid%8)*64 + bid/8
  int bid = blockIdx.x;
  int nid = ((bid & 7) << 6) | (bid >> 3);
  int bm = nid >> 3, bn = nid & 7;
  size_t aBase = (size_t)bm * 128 * KDIM;
  size_t bBase = (size_t)bn * 128 * KDIM;
  // staging: round j (0..3): wave w covers rows [j*32 + w*8, +8); lane l -> row + (l>>3), col (l&7)*8
  int r0 = wave*8 + (lane >> 3);
  int c0 = (lane & 7) * 8;
  int wm = (wave >> 1) * 64, wn = (wave & 1) * 64;
  int la = lane & 15, lk = (lane >> 4) * 8;
  f32x4 acc[4][4];
#pragma unroll
  for (int m = 0; m < 4; ++m)
#pragma unroll
    for (int n = 0; n < 4; ++n) acc[m][n] = (f32x4){0.f, 0.f, 0.f, 0.f};

  for (int k0 = 0; k0 < KDIM; k0 += 64) {
    __syncthreads();
#pragma unroll
    for (int j = 0; j < 4; ++j) {
      __builtin_amdgcn_global_load_lds(
          (const __attribute__((address_space(1))) void*)(A + aBase + (size_t)(j*32 + r0)*KDIM + k0 + c0),
          (__attribute__((address_space(3))) void*)((char*)As + j*4096 + wave*1024), 16, 0, 0);
      __builtin_amdgcn_global_load_lds(
          (const __attribute__((address_space(1))) void*)(Bm + bBase + (size_t)(j*32 + r0)*KDIM + k0 + c0),
          (__attribute__((address_space(3))) void*)((char*)Bs + j*4096 + wave*1024), 16, 0, 0);
    }
    __syncthreads();
#pragma unroll
    for (int kk = 0; kk < 2; ++kk) {
      short8 af[4], bf[4];
#pragma unroll
      for (int m = 0; m < 4; ++m) af[m] = *(const short8*)&As[(wm + m*16 + la)*64 + kk*32 + lk];
#pragma unroll
      for (int n = 0; n < 4; ++n) bf[n] = *(const short8*)&Bs[(wn + n*16 + la)*64 + kk*32 + lk];
#pragma unroll
      for (int m = 0; m < 4; ++m)
#pragma unroll
        for (int n = 0; n < 4; ++n)
          acc[m][n] = __builtin_amdgcn_mfma_f32_16x16x32_bf16(af[m], bf[n], acc[m][n], 0, 0, 0);
    }
  }

  int orow0 = bm*128 + wm + (lane >> 4)*4;
  int ocol0 = bn*128 + wn + la;
#pragma unroll
  for (int m = 0; m < 4; ++m)
#pragma unroll
    for (int n = 0; n < 4; ++n)
#pragma unroll
      for (int j = 0; j < 4; ++j)
        C[(size_t)(orow0 + m*16 + j)*NDIM + ocol0 + n*16] = acc[m][n][j];
}

extern "C" void kernel_launch(void* const* d_in, const int* in_sizes, int n_in,
                              void* d_out, int out_size, void* d_ws, size_t ws_size,
                              hipStream_t stream) {
  const float* x = (const float*)d_in[0];
  const float* w = (const float*)d_in[1];
  float* out = (float*)d_out;
  char* ws = (char*)d_ws;
  u16* Bmat = (u16*)ws;                              // 2 MB
  u16* Abf  = (u16*)(ws + 2*1024*1024);              // 16 MB

  normalize_rows<<<BATCH/4, 256, 0, stream>>>(x, Abf);
  build_M<<<DIMQ/4, 256, 0, stream>>>(w, Bmat);
  gemm_bt<<<(BATCH/128)*(NDIM/128), 256, 0, stream>>>(Abf, Bmat, out);
}

// Round 3
// 78.814 us; speedup vs baseline: 1.0084x; 1.0084x over previous
//
#include <hip/hip_runtime.h>
#include <stdint.h>

typedef uint16_t u16;
typedef __attribute__((ext_vector_type(4))) float f32x4;
typedef __attribute__((ext_vector_type(8))) short short8;
typedef __attribute__((ext_vector_type(4))) float float4v;
typedef __attribute__((ext_vector_type(4))) uint16_t u16x4;
typedef __attribute__((ext_vector_type(8))) uint16_t u16x8;

#define DIMQ 1024
#define BATCH 8192
#define KDIM 1024
#define NDIM 1024

__device__ __forceinline__ u16 f2bf(float f) {
  uint32_t u = __float_as_uint(f);
  u += 0x7fffu + ((u >> 16) & 1u);
  return (u16)(u >> 16);
}

// complex 2x2 layout: {00r,00i, 01r,01i, 10r,10i, 11r,11i}
__device__ inline void cmul2x2(float* O, const float* A, const float* B) {
  for (int r = 0; r < 2; ++r)
    for (int c = 0; c < 2; ++c) {
      float re = 0.f, im = 0.f;
      for (int j = 0; j < 2; ++j) {
        float ar = A[(r*2+j)*2], ai = A[(r*2+j)*2+1];
        float br = B[(j*2+c)*2], bi = B[(j*2+c)*2+1];
        re += ar*br - ai*bi;
        im += ar*bi + ai*br;
      }
      O[(r*2+c)*2]   = re;
      O[(r*2+c)*2+1] = im;
    }
}
__device__ inline void mk_rx(float* m, float t) {
  float s, c; sincosf(0.5f*t, &s, &c);
  m[0]=c; m[1]=0; m[2]=0; m[3]=-s; m[4]=0; m[5]=-s; m[6]=c; m[7]=0;
}
__device__ inline void mk_ry(float* m, float t) {
  float s, c; sincosf(0.5f*t, &s, &c);
  m[0]=c; m[1]=0; m[2]=-s; m[3]=0; m[4]=s; m[5]=0; m[6]=c; m[7]=0;
}
__device__ inline void mk_rz(float* m, float t) {
  float s, c; sincosf(0.5f*t, &s, &c);
  m[0]=c; m[1]=-s; m[2]=0; m[3]=0; m[4]=0; m[5]=0; m[6]=c; m[7]=s;
}

// Row-normalize x (fp32) -> bf16. One wave per row, 4 rows per block.
// Block 0 threads 0..49 additionally compute the 50 fused adjoint gate
// matrices into global mats[] (build_M, launched after, consumes them).
__global__ __launch_bounds__(256) void normalize_rows(const float* __restrict__ x,
                                                      u16* __restrict__ Abf,
                                                      const float* __restrict__ w,
                                                      float* __restrict__ mats) {
  int lane = threadIdx.x & 63, wave = threadIdx.x >> 6;
  int row = blockIdx.x * 4 + wave;
  const float* xr = x + (size_t)row * DIMQ;
  float4v v[4];
  float ss = 0.f;
#pragma unroll
  for (int j = 0; j < 4; ++j) {
    v[j] = *(const float4v*)(xr + j*256 + lane*4);
    ss += v[j][0]*v[j][0] + v[j][1]*v[j][1] + v[j][2]*v[j][2] + v[j][3]*v[j][3];
  }
#pragma unroll
  for (int off = 32; off; off >>= 1) ss += __shfl_xor(ss, off, 64);
  float inv = 1.0f / fmaxf(sqrtf(ss), 1e-12f);
  u16* orow = Abf + (size_t)row * DIMQ;
#pragma unroll
  for (int j = 0; j < 4; ++j) {
    u16x4 o;
#pragma unroll
    for (int e = 0; e < 4; ++e) o[e] = f2bf(v[j][e] * inv);
    *(u16x4*)(orow + j*256 + lane*4) = o;
  }
  // fused adjoint gate matrices (stage 0: RY(-a)RZ(-b)RY(-c); stages 1..4: RX RY RZ of layer 3-s)
  if (blockIdx.x == 0 && threadIdx.x < 50) {
    int t = threadIdx.x;
    float A[8], B[8], C[8], T[8], O[8];
    if (t < 10) {
      mk_ry(A, -w[120 + t]);
      mk_rz(B, -w[130 + t]);
      mk_ry(C, -w[140 + t]);
    } else {
      int s = (t - 10) / 10, q = (t - 10) % 10, l = 3 - s;
      mk_rx(A, -w[l*30 + q]);
      mk_ry(B, -w[l*30 + 10 + q]);
      mk_rz(C, -w[l*30 + 20 + q]);
    }
    cmul2x2(T, A, B);
    cmul2x2(O, T, C);
#pragma unroll
    for (int j = 0; j < 8; ++j) mats[t*8 + j] = O[j];
  }
}

// One WAVE (one 64-thread block) per basis state d. State (1024 complex amps)
// lives in registers: lane L holds amps x = L*16 + r, r=0..15.
// CNOT-ring permutation new[x]=old[sigma(x)] done entirely in-register:
//   sigma is GF(2)-linear: reg_src = T(r) ^ (15*PL(target)), lane_src = Lam(L) ^ (32*parity(r)),
//   and PL(target) == bit0 of lane_src, so each SOURCE lane pre-selects
//   prep[r] = old[T(r) ^ (15*(lane&1))] (cndmask), then one bpermute per reg.
// No LDS, no barriers. Gate coefficients via uniform (scalar) loads from mats.
__global__ __launch_bounds__(64) void build_M(const float* __restrict__ mats,
                                              u16* __restrict__ Bmat) {
  const int lane = threadIdx.x;
  const int d = blockIdx.x;

  // fixed source-lane map for the permutation
  int b0 = __builtin_popcount(lane & 0x3f) & 1;   // PL
  int b1 = __builtin_popcount(lane & 0x3e) & 1;
  int b2 = __builtin_popcount(lane & 0x3c) & 1;
  int b3 = __builtin_popcount(lane & 0x38) & 1;
  int b4 = __builtin_popcount(lane & 0x30) & 1;
  int b5 = b0 ^ (lane >> 5);                      // PL ^ L5
  int lsrcE = b0 | (b1<<1) | (b2<<2) | (b3<<3) | (b4<<4) | (b5<<5);
  int lsrcO = lsrcE ^ 32;
  bool oddlane = lane & 1;

  float ar[16], ai[16];
#pragma unroll
  for (int r = 0; r < 16; ++r) {
    ar[r] = ((lane << 4) + r == d) ? 1.0f : 0.0f;
    ai[r] = 0.0f;
  }

  for (int stage = 0; stage < 5; ++stage) {
    if (stage) {
      // adjoint CNOT-ring permutation, in-register
      static const int T[16] = {0,1,3,2,7,6,4,5,15,14,12,13,8,9,11,10};
      float pr_[16], pi_[16];
#pragma unroll
      for (int r = 0; r < 16; ++r) {
        pr_[r] = oddlane ? ar[T[r]^15] : ar[T[r]];
        pi_[r] = oddlane ? ai[T[r]^15] : ai[T[r]];
      }
#pragma unroll
      for (int r = 0; r < 16; ++r) {
        int src = (__builtin_popcount((unsigned)r) & 1) ? lsrcO : lsrcE;
        ar[r] = __shfl(pr_[r], src, 64);
        ai[r] = __shfl(pi_[r], src, 64);
      }
    }
    // gates q = 0..5: act on lane bits (amp bit 9-q -> lane bit 5-q)
#pragma unroll
    for (int q = 0; q < 6; ++q) {
      const float* g = mats + (stage*10 + q)*8;   // uniform -> s_load
      float u00r=g[0], u00i=g[1], u01r=g[2], u01i=g[3];
      float u10r=g[4], u10i=g[5], u11r=g[6], u11i=g[7];
      const int pb = 5 - q;
      int bit = (lane >> pb) & 1;
      float cmr = bit ? u11r : u00r, cmi = bit ? u11i : u00i;
      float cor = bit ? u10r : u01r, coi = bit ? u10i : u01i;
#pragma unroll
      for (int r = 0; r < 16; ++r) {
        float otr = __shfl_xor(ar[r], 1 << pb, 64);
        float oti = __shfl_xor(ai[r], 1 << pb, 64);
        float nr = cmr*ar[r] - cmi*ai[r] + cor*otr - coi*oti;
        float ni = cmr*ai[r] + cmi*ar[r] + cor*oti + coi*otr;
        ar[r] = nr; ai[r] = ni;
      }
    }
    // gates q = 6..9: act on reg bits (amp bit 9-q in 3..0)
#pragma unroll
    for (int q = 6; q < 10; ++q) {
      const int p = 9 - q;
      const float* g = mats + (stage*10 + q)*8;   // uniform -> s_load
      float u00r=g[0], u00i=g[1], u01r=g[2], u01i=g[3];
      float u10r=g[4], u10i=g[5], u11r=g[6], u11i=g[7];
#pragma unroll
      for (int h = 0; h < 8; ++h) {
        int r0 = ((h >> p) << (p+1)) | (h & ((1 << p) - 1));
        int r1 = r0 | (1 << p);
        float a0r = ar[r0], a0i = ai[r0], a1r = ar[r1], a1i = ai[r1];
        ar[r0] = u00r*a0r - u00i*a0i + u01r*a1r - u01i*a1i;
        ai[r0] = u00r*a0i + u00i*a0r + u01r*a1i + u01i*a1r;
        ar[r1] = u10r*a0r - u10i*a0i + u11r*a1r - u11i*a1i;
        ai[r1] = u10r*a0i + u10i*a0r + u11r*a1i + u11i*a1r;
      }
    }
  }

  // write row d of M = Re(U) as bf16; each lane writes 32 contiguous bytes
  u16x8 v0, v1;
#pragma unroll
  for (int r = 0; r < 8; ++r) v0[r] = f2bf(ar[r]);
#pragma unroll
  for (int r = 0; r < 8; ++r) v1[r] = f2bf(ar[8 + r]);
  u16* row = Bmat + (size_t)d * DIMQ + lane * 16;
  *(u16x8*)row = v0;
  *(u16x8*)(row + 8) = v1;
}

// C[8192,1024] = A[8192,1024] * B[1024,1024]^T   (bf16 in, fp32 out)
// 128x128 tile, BK=32, 4 waves (2x2 of 64x64), 16x16x32 bf16 MFMA,
// global_load_lds width-16 staging (m97 structure).
__global__ __launch_bounds__(256) void gemm_bt(const u16* __restrict__ A,
                                               const u16* __restrict__ Bm,
                                               float* __restrict__ C) {
  __shared__ u16 As[128*32];
  __shared__ u16 Bs[128*32];
  int t = threadIdx.x, lane = t & 63, wave = t >> 6;
  // XCD-aware swizzle: nwg=512, 512%8==0 -> nid=(bid%8)*64 + bid/8
  int bid = blockIdx.x;
  int nid = ((bid & 7) << 6) | (bid >> 3);
  int bm = nid >> 3, bn = nid & 7;
  size_t aBase = (size_t)bm * 128 * KDIM;
  size_t bBase = (size_t)bn * 128 * KDIM;
  int r0 = wave*16 + (lane >> 2);     // row within a 64-row chunk
  int c0 = (lane & 3) * 8;            // col (elements) within the 32-wide k-slab
  int wm = (wave >> 1) * 64, wn = (wave & 1) * 64;
  int la = lane & 15, lk = (lane >> 4) * 8;
  f32x4 acc[4][4];
#pragma unroll
  for (int m = 0; m < 4; ++m)
#pragma unroll
    for (int n = 0; n < 4; ++n) acc[m][n] = (f32x4){0.f, 0.f, 0.f, 0.f};

  for (int k0 = 0; k0 < KDIM; k0 += 32) {
    __syncthreads();
#pragma unroll
    for (int j = 0; j < 2; ++j) {
      __builtin_amdgcn_global_load_lds(
          (const __attribute__((address_space(1))) void*)(A + aBase + (size_t)(j*64 + r0)*KDIM + k0 + c0),
          (__attribute__((address_space(3))) void*)((char*)As + j*4096 + wave*1024), 16, 0, 0);
      __builtin_amdgcn_global_load_lds(
          (const __attribute__((address_space(1))) void*)(Bm + bBase + (size_t)(j*64 + r0)*KDIM + k0 + c0),
          (__attribute__((address_space(3))) void*)((char*)Bs + j*4096 + wave*1024), 16, 0, 0);
    }
    __syncthreads();
    short8 af[4], bf[4];
#pragma unroll
    for (int m = 0; m < 4; ++m) af[m] = *(const short8*)&As[(wm + m*16 + la)*32 + lk];
#pragma unroll
    for (int n = 0; n < 4; ++n) bf[n] = *(const short8*)&Bs[(wn + n*16 + la)*32 + lk];
#pragma unroll
    for (int m = 0; m < 4; ++m)
#pragma unroll
      for (int n = 0; n < 4; ++n)
        acc[m][n] = __builtin_amdgcn_mfma_f32_16x16x32_bf16(af[m], bf[n], acc[m][n], 0, 0, 0);
  }

  int orow0 = bm*128 + wm + (lane >> 4)*4;
  int ocol0 = bn*128 + wn + la;
#pragma unroll
  for (int m = 0; m < 4; ++m)
#pragma unroll
    for (int n = 0; n < 4; ++n)
#pragma unroll
      for (int j = 0; j < 4; ++j)
        C[(size_t)(orow0 + m*16 + j)*NDIM + ocol0 + n*16] = acc[m][n][j];
}

extern "C" void kernel_launch(void* const* d_in, const int* in_sizes, int n_in,
                              void* d_out, int out_size, void* d_ws, size_t ws_size,
                              hipStream_t stream) {
  const float* x = (const float*)d_in[0];
  const float* w = (const float*)d_in[1];
  float* out = (float*)d_out;
  char* ws = (char*)d_ws;
  float* mats = (float*)ws;                                  // 1600 B
  u16* Bmat   = (u16*)(ws + 4096);                           // 2 MB
  u16* Abf    = (u16*)(ws + 4096 + 2*1024*1024);             // 16 MB

  normalize_rows<<<BATCH/4, 256, 0, stream>>>(x, Abf, w, mats);
  build_M<<<DIMQ, 64, 0, stream>>>(mats, Bmat);
  gemm_bt<<<(BATCH/128)*(NDIM/128), 256, 0, stream>>>(Abf, Bmat, out);
}

// Round 4
// 75.490 us; speedup vs baseline: 1.0528x; 1.0440x over previous
//
#include <hip/hip_runtime.h>
#include <stdint.h>

typedef uint16_t u16;
typedef __attribute__((ext_vector_type(4))) float f32x4;
typedef __attribute__((ext_vector_type(8))) short short8;
typedef __attribute__((ext_vector_type(4))) float float4v;
typedef __attribute__((ext_vector_type(4))) uint16_t u16x4;
typedef __attribute__((ext_vector_type(8))) uint16_t u16x8;

#define DIMQ 1024
#define BATCH 8192
#define KDIM 1024
#define NDIM 1024

__device__ __forceinline__ u16 f2bf(float f) {
  uint32_t u = __float_as_uint(f);
  u += 0x7fffu + ((u >> 16) & 1u);
  return (u16)(u >> 16);
}

// cross-lane xor exchange; DPP (VALU pipe) for masks 1,2,8; ds_swizzle for 4,16;
// bpermute-based __shfl_xor only for 32.
template<int MASK>
__device__ __forceinline__ float lane_xor(float x) {
  if constexpr (MASK == 1)
    return __int_as_float(__builtin_amdgcn_update_dpp(0, __float_as_int(x), 0xB1, 0xF, 0xF, true));
  else if constexpr (MASK == 2)
    return __int_as_float(__builtin_amdgcn_update_dpp(0, __float_as_int(x), 0x4E, 0xF, 0xF, true));
  else if constexpr (MASK == 8)
    return __int_as_float(__builtin_amdgcn_update_dpp(0, __float_as_int(x), 0x128, 0xF, 0xF, true));
  else if constexpr (MASK == 4)
    return __int_as_float(__builtin_amdgcn_ds_swizzle(__float_as_int(x), 0x101F));
  else if constexpr (MASK == 16)
    return __int_as_float(__builtin_amdgcn_ds_swizzle(__float_as_int(x), 0x401F));
  else
    return __shfl_xor(x, 32, 64);
}

// one cross-lane gate: batched partner fetch (ILP), then FMAs
template<int MASK>
__device__ __forceinline__ void lane_gate(float* ar, float* ai,
                                          const float* __restrict__ g, int lane) {
  float u00r = g[0], u00i = g[1], u01r = g[2], u01i = g[3];
  float u10r = g[4], u10i = g[5], u11r = g[6], u11i = g[7];
  bool hi = (lane & MASK) != 0;
  float cmr = hi ? u11r : u00r, cmi = hi ? u11i : u00i;
  float cor = hi ? u10r : u01r, coi = hi ? u10i : u01i;
  float otr[16], oti[16];
#pragma unroll
  for (int r = 0; r < 16; ++r) otr[r] = lane_xor<MASK>(ar[r]);
#pragma unroll
  for (int r = 0; r < 16; ++r) oti[r] = lane_xor<MASK>(ai[r]);
#pragma unroll
  for (int r = 0; r < 16; ++r) {
    float nr = cmr*ar[r] - cmi*ai[r] + cor*otr[r] - coi*oti[r];
    float ni = cmr*ai[r] + cmi*ar[r] + cor*oti[r] + coi*otr[r];
    ar[r] = nr; ai[r] = ni;
  }
}

// complex 2x2 layout: {00r,00i, 01r,01i, 10r,10i, 11r,11i}
__device__ inline void cmul2x2(float* O, const float* A, const float* B) {
  for (int r = 0; r < 2; ++r)
    for (int c = 0; c < 2; ++c) {
      float re = 0.f, im = 0.f;
      for (int j = 0; j < 2; ++j) {
        float ar = A[(r*2+j)*2], ai = A[(r*2+j)*2+1];
        float br = B[(j*2+c)*2], bi = B[(j*2+c)*2+1];
        re += ar*br - ai*bi;
        im += ar*bi + ai*br;
      }
      O[(r*2+c)*2]   = re;
      O[(r*2+c)*2+1] = im;
    }
}
__device__ inline void mk_rx(float* m, float t) {
  float s, c; sincosf(0.5f*t, &s, &c);
  m[0]=c; m[1]=0; m[2]=0; m[3]=-s; m[4]=0; m[5]=-s; m[6]=c; m[7]=0;
}
__device__ inline void mk_ry(float* m, float t) {
  float s, c; sincosf(0.5f*t, &s, &c);
  m[0]=c; m[1]=0; m[2]=-s; m[3]=0; m[4]=s; m[5]=0; m[6]=c; m[7]=0;
}
__device__ inline void mk_rz(float* m, float t) {
  float s, c; sincosf(0.5f*t, &s, &c);
  m[0]=c; m[1]=-s; m[2]=0; m[3]=0; m[4]=0; m[5]=0; m[6]=c; m[7]=s;
}

// Row-normalize x (fp32) -> bf16. One wave per row, 4 rows per block.
// Block 0 threads 0..49 additionally compute the 50 fused adjoint gate
// matrices into global mats[] (consumed by build_M, launched after).
__global__ __launch_bounds__(256) void normalize_rows(const float* __restrict__ x,
                                                      u16* __restrict__ Abf,
                                                      const float* __restrict__ w,
                                                      float* __restrict__ mats) {
  int lane = threadIdx.x & 63, wave = threadIdx.x >> 6;
  int row = blockIdx.x * 4 + wave;
  const float* xr = x + (size_t)row * DIMQ;
  float4v v[4];
  float ss = 0.f;
#pragma unroll
  for (int j = 0; j < 4; ++j) {
    v[j] = *(const float4v*)(xr + j*256 + lane*4);
    ss += v[j][0]*v[j][0] + v[j][1]*v[j][1] + v[j][2]*v[j][2] + v[j][3]*v[j][3];
  }
#pragma unroll
  for (int off = 32; off; off >>= 1) ss += __shfl_xor(ss, off, 64);
  float inv = 1.0f / fmaxf(sqrtf(ss), 1e-12f);
  u16* orow = Abf + (size_t)row * DIMQ;
#pragma unroll
  for (int j = 0; j < 4; ++j) {
    u16x4 o;
#pragma unroll
    for (int e = 0; e < 4; ++e) o[e] = f2bf(v[j][e] * inv);
    *(u16x4*)(orow + j*256 + lane*4) = o;
  }
  if (blockIdx.x == 0 && threadIdx.x < 50) {
    int t = threadIdx.x;
    float A[8], B[8], C[8], T[8], O[8];
    if (t < 10) {
      mk_ry(A, -w[120 + t]);
      mk_rz(B, -w[130 + t]);
      mk_ry(C, -w[140 + t]);
    } else {
      int s = (t - 10) / 10, q = (t - 10) % 10, l = 3 - s;
      mk_rx(A, -w[l*30 + q]);
      mk_ry(B, -w[l*30 + 10 + q]);
      mk_rz(C, -w[l*30 + 20 + q]);
    }
    cmul2x2(T, A, B);
    cmul2x2(O, T, C);
#pragma unroll
    for (int j = 0; j < 8; ++j) mats[t*8 + j] = O[j];
  }
}

// One WAVE (64-thread block) per basis state d. 1024 complex amps in registers:
// lane L holds amps x = L*16 + r. Cross-lane gates via DPP/swizzle/shfl (see
// lane_xor); CNOT-ring permutation in-register via GF(2)-linear source map.
__global__ __launch_bounds__(64) void build_M(const float* __restrict__ mats,
                                              u16* __restrict__ Bmat) {
  const int lane = threadIdx.x;
  const int d = blockIdx.x;

  // fixed source-lane map for the permutation
  int b0 = __builtin_popcount(lane & 0x3f) & 1;   // PL
  int b1 = __builtin_popcount(lane & 0x3e) & 1;
  int b2 = __builtin_popcount(lane & 0x3c) & 1;
  int b3 = __builtin_popcount(lane & 0x38) & 1;
  int b4 = __builtin_popcount(lane & 0x30) & 1;
  int b5 = b0 ^ (lane >> 5);                      // PL ^ L5
  int lsrcE = b0 | (b1<<1) | (b2<<2) | (b3<<3) | (b4<<4) | (b5<<5);
  int lsrcO = lsrcE ^ 32;
  bool oddlane = lane & 1;

  float ar[16], ai[16];
#pragma unroll
  for (int r = 0; r < 16; ++r) {
    ar[r] = ((lane << 4) + r == d) ? 1.0f : 0.0f;
    ai[r] = 0.0f;
  }

  for (int stage = 0; stage < 5; ++stage) {
    if (stage) {
      // adjoint CNOT-ring permutation, in-register, batched
      static const int T[16] = {0,1,3,2,7,6,4,5,15,14,12,13,8,9,11,10};
      float pr_[16], pi_[16];
#pragma unroll
      for (int r = 0; r < 16; ++r) {
        pr_[r] = oddlane ? ar[T[r]^15] : ar[T[r]];
        pi_[r] = oddlane ? ai[T[r]^15] : ai[T[r]];
      }
#pragma unroll
      for (int r = 0; r < 16; ++r) {
        int src = (__builtin_popcount((unsigned)r) & 1) ? lsrcO : lsrcE;
        ar[r] = __shfl(pr_[r], src, 64);
        ai[r] = __shfl(pi_[r], src, 64);
      }
    }
    const float* gs = mats + stage * 80;
    // cross-lane gates: amp bits 9..4 -> lane masks 32..1
    lane_gate<32>(ar, ai, gs + 0, lane);
    lane_gate<16>(ar, ai, gs + 8, lane);
    lane_gate<8>(ar, ai, gs + 16, lane);
    lane_gate<4>(ar, ai, gs + 24, lane);
    lane_gate<2>(ar, ai, gs + 32, lane);
    lane_gate<1>(ar, ai, gs + 40, lane);
    // in-register gates: amp bits 3..0
#pragma unroll
    for (int q = 6; q < 10; ++q) {
      const int p = 9 - q;
      const float* g = gs + q*8;
      float u00r=g[0], u00i=g[1], u01r=g[2], u01i=g[3];
      float u10r=g[4], u10i=g[5], u11r=g[6], u11i=g[7];
#pragma unroll
      for (int h = 0; h < 8; ++h) {
        int r0 = ((h >> p) << (p+1)) | (h & ((1 << p) - 1));
        int r1 = r0 | (1 << p);
        float a0r = ar[r0], a0i = ai[r0], a1r = ar[r1], a1i = ai[r1];
        ar[r0] = u00r*a0r - u00i*a0i + u01r*a1r - u01i*a1i;
        ai[r0] = u00r*a0i + u00i*a0r + u01r*a1i + u01i*a1r;
        ar[r1] = u10r*a0r - u10i*a0i + u11r*a1r - u11i*a1i;
        ai[r1] = u10r*a0i + u10i*a0r + u11r*a1i + u11i*a1r;
      }
    }
  }

  // write row d of M = Re(U) as bf16; each lane writes 32 contiguous bytes
  u16x8 v0, v1;
#pragma unroll
  for (int r = 0; r < 8; ++r) v0[r] = f2bf(ar[r]);
#pragma unroll
  for (int r = 0; r < 8; ++r) v1[r] = f2bf(ar[8 + r]);
  u16* row = Bmat + (size_t)d * DIMQ + lane * 16;
  *(u16x8*)row = v0;
  *(u16x8*)(row + 8) = v1;
}

// C[8192,1024] = A[8192,1024] * B[1024,1024]^T   (bf16 in, fp32 out)
// 128x128 tile, BK=32, 4 waves (2x2 of 64x64), 16x16x32 bf16 MFMA,
// global_load_lds width-16 staging (m97 structure).
__global__ __launch_bounds__(256) void gemm_bt(const u16* __restrict__ A,
                                               const u16* __restrict__ Bm,
                                               float* __restrict__ C) {
  __shared__ u16 As[128*32];
  __shared__ u16 Bs[128*32];
  int t = threadIdx.x, lane = t & 63, wave = t >> 6;
  int bid = blockIdx.x;
  int nid = ((bid & 7) << 6) | (bid >> 3);
  int bm = nid >> 3, bn = nid & 7;
  size_t aBase = (size_t)bm * 128 * KDIM;
  size_t bBase = (size_t)bn * 128 * KDIM;
  int r0 = wave*16 + (lane >> 2);
  int c0 = (lane & 3) * 8;
  int wm = (wave >> 1) * 64, wn = (wave & 1) * 64;
  int la = lane & 15, lk = (lane >> 4) * 8;
  f32x4 acc[4][4];
#pragma unroll
  for (int m = 0; m < 4; ++m)
#pragma unroll
    for (int n = 0; n < 4; ++n) acc[m][n] = (f32x4){0.f, 0.f, 0.f, 0.f};

  for (int k0 = 0; k0 < KDIM; k0 += 32) {
    __syncthreads();
#pragma unroll
    for (int j = 0; j < 2; ++j) {
      __builtin_amdgcn_global_load_lds(
          (const __attribute__((address_space(1))) void*)(A + aBase + (size_t)(j*64 + r0)*KDIM + k0 + c0),
          (__attribute__((address_space(3))) void*)((char*)As + j*4096 + wave*1024), 16, 0, 0);
      __builtin_amdgcn_global_load_lds(
          (const __attribute__((address_space(1))) void*)(Bm + bBase + (size_t)(j*64 + r0)*KDIM + k0 + c0),
          (__attribute__((address_space(3))) void*)((char*)Bs + j*4096 + wave*1024), 16, 0, 0);
    }
    __syncthreads();
    short8 af[4], bf[4];
#pragma unroll
    for (int m = 0; m < 4; ++m) af[m] = *(const short8*)&As[(wm + m*16 + la)*32 + lk];
#pragma unroll
    for (int n = 0; n < 4; ++n) bf[n] = *(const short8*)&Bs[(wn + n*16 + la)*32 + lk];
#pragma unroll
    for (int m = 0; m < 4; ++m)
#pragma unroll
      for (int n = 0; n < 4; ++n)
        acc[m][n] = __builtin_amdgcn_mfma_f32_16x16x32_bf16(af[m], bf[n], acc[m][n], 0, 0, 0);
  }

  int orow0 = bm*128 + wm + (lane >> 4)*4;
  int ocol0 = bn*128 + wn + la;
#pragma unroll
  for (int m = 0; m < 4; ++m)
#pragma unroll
    for (int n = 0; n < 4; ++n)
#pragma unroll
      for (int j = 0; j < 4; ++j)
        C[(size_t)(orow0 + m*16 + j)*NDIM + ocol0 + n*16] = acc[m][n][j];
}

extern "C" void kernel_launch(void* const* d_in, const int* in_sizes, int n_in,
                              void* d_out, int out_size, void* d_ws, size_t ws_size,
                              hipStream_t stream) {
  const float* x = (const float*)d_in[0];
  const float* w = (const float*)d_in[1];
  float* out = (float*)d_out;
  char* ws = (char*)d_ws;
  float* mats = (float*)ws;                                  // 1600 B
  u16* Bmat   = (u16*)(ws + 4096);                           // 2 MB
  u16* Abf    = (u16*)(ws + 4096 + 2*1024*1024);             // 16 MB

  normalize_rows<<<BATCH/4, 256, 0, stream>>>(x, Abf, w, mats);
  build_M<<<DIMQ, 64, 0, stream>>>(mats, Bmat);
  gemm_bt<<<(BATCH/128)*(NDIM/128), 256, 0, stream>>>(Abf, Bmat, out);
}

// Round 5
// 66.796 us; speedup vs baseline: 1.1898x; 1.1302x over previous
//
#include <hip/hip_runtime.h>
#include <stdint.h>

typedef uint16_t u16;
typedef __attribute__((ext_vector_type(4))) float f32x4;
typedef __attribute__((ext_vector_type(8))) short short8;
typedef __attribute__((ext_vector_type(4))) float float4v;
typedef __attribute__((ext_vector_type(4))) uint16_t u16x4;
typedef __attribute__((ext_vector_type(8))) uint16_t u16x8;

#define DIMQ 1024
#define BATCH 8192
#define KDIM 1024
#define NDIM 1024

#define RDL(v, l) __int_as_float(__builtin_amdgcn_readlane(__float_as_int(v), (l)))

__device__ __forceinline__ u16 f2bf(float f) {
  uint32_t u = __float_as_uint(f);
  u += 0x7fffu + ((u >> 16) & 1u);
  return (u16)(u >> 16);
}

// cross-lane xor exchange; DPP (VALU pipe) for masks 1,2,8; ds_swizzle for 4,16;
// bpermute-based __shfl_xor only for 32.
template<int MASK>
__device__ __forceinline__ float lane_xor(float x) {
  if constexpr (MASK == 1)
    return __int_as_float(__builtin_amdgcn_update_dpp(0, __float_as_int(x), 0xB1, 0xF, 0xF, true));
  else if constexpr (MASK == 2)
    return __int_as_float(__builtin_amdgcn_update_dpp(0, __float_as_int(x), 0x4E, 0xF, 0xF, true));
  else if constexpr (MASK == 8)
    return __int_as_float(__builtin_amdgcn_update_dpp(0, __float_as_int(x), 0x128, 0xF, 0xF, true));
  else if constexpr (MASK == 4)
    return __int_as_float(__builtin_amdgcn_ds_swizzle(__float_as_int(x), 0x101F));
  else if constexpr (MASK == 16)
    return __int_as_float(__builtin_amdgcn_ds_swizzle(__float_as_int(x), 0x401F));
  else
    return __shfl_xor(x, 32, 64);
}

// one cross-lane gate: batched partner fetch (ILP), then FMAs
template<int MASK>
__device__ __forceinline__ void lane_gate(float* ar, float* ai, int lane,
    float u00r, float u00i, float u01r, float u01i,
    float u10r, float u10i, float u11r, float u11i) {
  bool hi = (lane & MASK) != 0;
  float cmr = hi ? u11r : u00r, cmi = hi ? u11i : u00i;
  float cor = hi ? u10r : u01r, coi = hi ? u10i : u01i;
  float otr[16], oti[16];
#pragma unroll
  for (int r = 0; r < 16; ++r) otr[r] = lane_xor<MASK>(ar[r]);
#pragma unroll
  for (int r = 0; r < 16; ++r) oti[r] = lane_xor<MASK>(ai[r]);
#pragma unroll
  for (int r = 0; r < 16; ++r) {
    float nr = cmr*ar[r] - cmi*ai[r] + cor*otr[r] - coi*oti[r];
    float ni = cmr*ai[r] + cmi*ar[r] + cor*oti[r] + coi*otr[r];
    ar[r] = nr; ai[r] = ni;
  }
}

// complex 2x2 layout: {00r,00i, 01r,01i, 10r,10i, 11r,11i}
__device__ inline void cmul2x2(float* O, const float* A, const float* B) {
  for (int r = 0; r < 2; ++r)
    for (int c = 0; c < 2; ++c) {
      float re = 0.f, im = 0.f;
      for (int j = 0; j < 2; ++j) {
        float ar = A[(r*2+j)*2], ai = A[(r*2+j)*2+1];
        float br = B[(j*2+c)*2], bi = B[(j*2+c)*2+1];
        re += ar*br - ai*bi;
        im += ar*bi + ai*br;
      }
      O[(r*2+c)*2]   = re;
      O[(r*2+c)*2+1] = im;
    }
}
__device__ inline void mk_rx(float* m, float t) {
  float s, c; sincosf(0.5f*t, &s, &c);
  m[0]=c; m[1]=0; m[2]=0; m[3]=-s; m[4]=0; m[5]=-s; m[6]=c; m[7]=0;
}
__device__ inline void mk_ry(float* m, float t) {
  float s, c; sincosf(0.5f*t, &s, &c);
  m[0]=c; m[1]=0; m[2]=-s; m[3]=0; m[4]=s; m[5]=0; m[6]=c; m[7]=0;
}
__device__ inline void mk_rz(float* m, float t) {
  float s, c; sincosf(0.5f*t, &s, &c);
  m[0]=c; m[1]=-s; m[2]=0; m[3]=0; m[4]=0; m[5]=0; m[6]=c; m[7]=s;
}

// Fused front kernel.
//   blocks [0, 256):    build_M — wave w handles basis state d = bid*4 + w.
//                       1024 complex amps in registers (lane L holds x = L*16+r).
//                       Gate coeffs: each wave computes all 50 fused 2x2s in
//                       lanes 0..49, fetched per-gate via v_readlane (no memory).
//                       Stage loop kept ROLLED (I$-resident body).
//   blocks [256, 2304): row-normalize x (fp32) -> bf16, 4 rows per block.
__global__ __launch_bounds__(256) void fused_front(const float* __restrict__ x,
                                                   const float* __restrict__ w,
                                                   u16* __restrict__ Abf,
                                                   u16* __restrict__ Bmat) {
  const int bid = blockIdx.x;
  const int lane = threadIdx.x & 63, wave = threadIdx.x >> 6;

  if (bid >= 256) {
    // ---- normalize path ----
    int row = (bid - 256) * 4 + wave;
    const float* xr = x + (size_t)row * DIMQ;
    float4v v[4];
    float ss = 0.f;
#pragma unroll
    for (int j = 0; j < 4; ++j) {
      v[j] = *(const float4v*)(xr + j*256 + lane*4);
      ss += v[j][0]*v[j][0] + v[j][1]*v[j][1] + v[j][2]*v[j][2] + v[j][3]*v[j][3];
    }
#pragma unroll
    for (int off = 32; off; off >>= 1) ss += __shfl_xor(ss, off, 64);
    float inv = 1.0f / fmaxf(sqrtf(ss), 1e-12f);
    u16* orow = Abf + (size_t)row * DIMQ;
#pragma unroll
    for (int j = 0; j < 4; ++j) {
      u16x4 o;
#pragma unroll
      for (int e = 0; e < 4; ++e) o[e] = f2bf(v[j][e] * inv);
      *(u16x4*)(orow + j*256 + lane*4) = o;
    }
    return;
  }

  // ---- build path ----
  const int d = bid * 4 + wave;

  // lanes 0..49: compute fused adjoint gate matrices into O0..O7
  float O0, O1, O2, O3, O4, O5, O6, O7;
  {
    float A[8], B[8], C[8], T8[8], O[8];
    int t = lane;
    if (t < 50) {
      if (t < 10) {
        mk_ry(A, -w[120 + t]);
        mk_rz(B, -w[130 + t]);
        mk_ry(C, -w[140 + t]);
      } else {
        int s = (t - 10) / 10, q = (t - 10) % 10, l = 3 - s;
        mk_rx(A, -w[l*30 + q]);
        mk_ry(B, -w[l*30 + 10 + q]);
        mk_rz(C, -w[l*30 + 20 + q]);
      }
      cmul2x2(T8, A, B);
      cmul2x2(O, T8, C);
    } else {
#pragma unroll
      for (int j = 0; j < 8; ++j) O[j] = 0.f;
    }
    O0=O[0]; O1=O[1]; O2=O[2]; O3=O[3]; O4=O[4]; O5=O[5]; O6=O[6]; O7=O[7];
  }

  // fixed source-lane map for the CNOT-ring permutation
  int b0 = __builtin_popcount(lane & 0x3f) & 1;   // PL
  int b1 = __builtin_popcount(lane & 0x3e) & 1;
  int b2 = __builtin_popcount(lane & 0x3c) & 1;
  int b3 = __builtin_popcount(lane & 0x38) & 1;
  int b4 = __builtin_popcount(lane & 0x30) & 1;
  int b5 = b0 ^ (lane >> 5);                      // PL ^ L5
  int lsrcE = b0 | (b1<<1) | (b2<<2) | (b3<<3) | (b4<<4) | (b5<<5);
  int lsrcO = lsrcE ^ 32;
  bool oddlane = lane & 1;

  float ar[16], ai[16];
#pragma unroll
  for (int r = 0; r < 16; ++r) {
    ar[r] = ((lane << 4) + r == d) ? 1.0f : 0.0f;
    ai[r] = 0.0f;
  }

#pragma clang loop unroll(disable)
  for (int stage = 0; stage < 5; ++stage) {
    if (stage) {
      // adjoint CNOT-ring permutation, in-register, batched
      static const int T[16] = {0,1,3,2,7,6,4,5,15,14,12,13,8,9,11,10};
      float pr_[16], pi_[16];
#pragma unroll
      for (int r = 0; r < 16; ++r) {
        pr_[r] = oddlane ? ar[T[r]^15] : ar[T[r]];
        pi_[r] = oddlane ? ai[T[r]^15] : ai[T[r]];
      }
#pragma unroll
      for (int r = 0; r < 16; ++r) {
        int src = (__builtin_popcount((unsigned)r) & 1) ? lsrcO : lsrcE;
        ar[r] = __shfl(pr_[r], src, 64);
        ai[r] = __shfl(pi_[r], src, 64);
      }
    }
    const int gbase = stage * 10;
    // cross-lane gates: amp bits 9..4 -> lane masks 32..1 (gates gbase+0..5)
    { int g = gbase + 0; lane_gate<32>(ar, ai, lane, RDL(O0,g),RDL(O1,g),RDL(O2,g),RDL(O3,g),RDL(O4,g),RDL(O5,g),RDL(O6,g),RDL(O7,g)); }
    { int g = gbase + 1; lane_gate<16>(ar, ai, lane, RDL(O0,g),RDL(O1,g),RDL(O2,g),RDL(O3,g),RDL(O4,g),RDL(O5,g),RDL(O6,g),RDL(O7,g)); }
    { int g = gbase + 2; lane_gate< 8>(ar, ai, lane, RDL(O0,g),RDL(O1,g),RDL(O2,g),RDL(O3,g),RDL(O4,g),RDL(O5,g),RDL(O6,g),RDL(O7,g)); }
    { int g = gbase + 3; lane_gate< 4>(ar, ai, lane, RDL(O0,g),RDL(O1,g),RDL(O2,g),RDL(O3,g),RDL(O4,g),RDL(O5,g),RDL(O6,g),RDL(O7,g)); }
    { int g = gbase + 4; lane_gate< 2>(ar, ai, lane, RDL(O0,g),RDL(O1,g),RDL(O2,g),RDL(O3,g),RDL(O4,g),RDL(O5,g),RDL(O6,g),RDL(O7,g)); }
    { int g = gbase + 5; lane_gate< 1>(ar, ai, lane, RDL(O0,g),RDL(O1,g),RDL(O2,g),RDL(O3,g),RDL(O4,g),RDL(O5,g),RDL(O6,g),RDL(O7,g)); }
    // in-register gates: amp bits 3..0 (gates gbase+6..9)
#pragma unroll
    for (int q = 6; q < 10; ++q) {
      const int p = 9 - q;
      int g = gbase + q;
      float u00r=RDL(O0,g), u00i=RDL(O1,g), u01r=RDL(O2,g), u01i=RDL(O3,g);
      float u10r=RDL(O4,g), u10i=RDL(O5,g), u11r=RDL(O6,g), u11i=RDL(O7,g);
#pragma unroll
      for (int h = 0; h < 8; ++h) {
        int r0 = ((h >> p) << (p+1)) | (h & ((1 << p) - 1));
        int r1 = r0 | (1 << p);
        float a0r = ar[r0], a0i = ai[r0], a1r = ar[r1], a1i = ai[r1];
        ar[r0] = u00r*a0r - u00i*a0i + u01r*a1r - u01i*a1i;
        ai[r0] = u00r*a0i + u00i*a0r + u01r*a1i + u01i*a1r;
        ar[r1] = u10r*a0r - u10i*a0i + u11r*a1r - u11i*a1i;
        ai[r1] = u10r*a0i + u10i*a0r + u11r*a1i + u11i*a1r;
      }
    }
  }

  // write row d of M = Re(U) as bf16; each lane writes 32 contiguous bytes
  u16x8 v0, v1;
#pragma unroll
  for (int r = 0; r < 8; ++r) v0[r] = f2bf(ar[r]);
#pragma unroll
  for (int r = 0; r < 8; ++r) v1[r] = f2bf(ar[8 + r]);
  u16* row = Bmat + (size_t)d * DIMQ + lane * 16;
  *(u16x8*)row = v0;
  *(u16x8*)(row + 8) = v1;
}

// C[8192,1024] = A[8192,1024] * B[1024,1024]^T   (bf16 in, fp32 out)
// 128x128 tile, BK=32, 4 waves (2x2 of 64x64), 16x16x32 bf16 MFMA,
// global_load_lds width-16 staging (m97 structure).
__global__ __launch_bounds__(256) void gemm_bt(const u16* __restrict__ A,
                                               const u16* __restrict__ Bm,
                                               float* __restrict__ C) {
  __shared__ u16 As[128*32];
  __shared__ u16 Bs[128*32];
  int t = threadIdx.x, lane = t & 63, wave = t >> 6;
  int bid = blockIdx.x;
  int nid = ((bid & 7) << 6) | (bid >> 3);
  int bm = nid >> 3, bn = nid & 7;
  size_t aBase = (size_t)bm * 128 * KDIM;
  size_t bBase = (size_t)bn * 128 * KDIM;
  int r0 = wave*16 + (lane >> 2);
  int c0 = (lane & 3) * 8;
  int wm = (wave >> 1) * 64, wn = (wave & 1) * 64;
  int la = lane & 15, lk = (lane >> 4) * 8;
  f32x4 acc[4][4];
#pragma unroll
  for (int m = 0; m < 4; ++m)
#pragma unroll
    for (int n = 0; n < 4; ++n) acc[m][n] = (f32x4){0.f, 0.f, 0.f, 0.f};

  for (int k0 = 0; k0 < KDIM; k0 += 32) {
    __syncthreads();
#pragma unroll
    for (int j = 0; j < 2; ++j) {
      __builtin_amdgcn_global_load_lds(
          (const __attribute__((address_space(1))) void*)(A + aBase + (size_t)(j*64 + r0)*KDIM + k0 + c0),
          (__attribute__((address_space(3))) void*)((char*)As + j*4096 + wave*1024), 16, 0, 0);
      __builtin_amdgcn_global_load_lds(
          (const __attribute__((address_space(1))) void*)(Bm + bBase + (size_t)(j*64 + r0)*KDIM + k0 + c0),
          (__attribute__((address_space(3))) void*)((char*)Bs + j*4096 + wave*1024), 16, 0, 0);
    }
    __syncthreads();
    short8 af[4], bf[4];
#pragma unroll
    for (int m = 0; m < 4; ++m) af[m] = *(const short8*)&As[(wm + m*16 + la)*32 + lk];
#pragma unroll
    for (int n = 0; n < 4; ++n) bf[n] = *(const short8*)&Bs[(wn + n*16 + la)*32 + lk];
#pragma unroll
    for (int m = 0; m < 4; ++m)
#pragma unroll
      for (int n = 0; n < 4; ++n)
        acc[m][n] = __builtin_amdgcn_mfma_f32_16x16x32_bf16(af[m], bf[n], acc[m][n], 0, 0, 0);
  }

  int orow0 = bm*128 + wm + (lane >> 4)*4;
  int ocol0 = bn*128 + wn + la;
#pragma unroll
  for (int m = 0; m < 4; ++m)
#pragma unroll
    for (int n = 0; n < 4; ++n)
#pragma unroll
      for (int j = 0; j < 4; ++j)
        C[(size_t)(orow0 + m*16 + j)*NDIM + ocol0 + n*16] = acc[m][n][j];
}

extern "C" void kernel_launch(void* const* d_in, const int* in_sizes, int n_in,
                              void* d_out, int out_size, void* d_ws, size_t ws_size,
                              hipStream_t stream) {
  const float* x = (const float*)d_in[0];
  const float* w = (const float*)d_in[1];
  float* out = (float*)d_out;
  char* ws = (char*)d_ws;
  u16* Bmat = (u16*)(ws + 4096);                             // 2 MB
  u16* Abf  = (u16*)(ws + 4096 + 2*1024*1024);               // 16 MB

  fused_front<<<256 + BATCH/4, 256, 0, stream>>>(x, w, Abf, Bmat);
  gemm_bt<<<(BATCH/128)*(NDIM/128), 256, 0, stream>>>(Abf, Bmat, out);
}

// Round 6
// 66.654 us; speedup vs baseline: 1.1924x; 1.0021x over previous
//
#include <hip/hip_runtime.h>
#include <stdint.h>

typedef uint16_t u16;
typedef __attribute__((ext_vector_type(4))) float f32x4;
typedef __attribute__((ext_vector_type(8))) short short8;
typedef __attribute__((ext_vector_type(4))) float float4v;
typedef __attribute__((ext_vector_type(4))) uint16_t u16x4;

#define DIMQ 1024
#define BATCH 8192
#define KDIM 1024
#define NDIM 1024
#define NBUILD 1024   /* build blocks (one per basis state) */

#define RDL(v, l) __int_as_float(__builtin_amdgcn_readlane(__float_as_int(v), (l)))

__device__ __forceinline__ u16 f2bf(float f) {
  uint32_t u = __float_as_uint(f);
  u += 0x7fffu + ((u >> 16) & 1u);
  return (u16)(u >> 16);
}

// cross-lane xor exchange; DPP (VALU pipe) for masks 1,2,8; ds_swizzle for 4,16;
// bpermute-based __shfl_xor only for 32.
template<int MASK>
__device__ __forceinline__ float lane_xor(float x) {
  if constexpr (MASK == 1)
    return __int_as_float(__builtin_amdgcn_update_dpp(0, __float_as_int(x), 0xB1, 0xF, 0xF, true));
  else if constexpr (MASK == 2)
    return __int_as_float(__builtin_amdgcn_update_dpp(0, __float_as_int(x), 0x4E, 0xF, 0xF, true));
  else if constexpr (MASK == 8)
    return __int_as_float(__builtin_amdgcn_update_dpp(0, __float_as_int(x), 0x128, 0xF, 0xF, true));
  else if constexpr (MASK == 4)
    return __int_as_float(__builtin_amdgcn_ds_swizzle(__float_as_int(x), 0x101F));
  else if constexpr (MASK == 16)
    return __int_as_float(__builtin_amdgcn_ds_swizzle(__float_as_int(x), 0x401F));
  else
    return __shfl_xor(x, 32, 64);
}

// one cross-lane gate on 4 amps: batched partner fetch, then FMAs
template<int MASK>
__device__ __forceinline__ void lane_gate4(float (&ar)[4], float (&ai)[4], int lane,
    float u00r, float u00i, float u01r, float u01i,
    float u10r, float u10i, float u11r, float u11i) {
  bool hi = (lane & MASK) != 0;
  float cmr = hi ? u11r : u00r, cmi = hi ? u11i : u00i;
  float cor = hi ? u10r : u01r, coi = hi ? u10i : u01i;
  float otr[4], oti[4];
#pragma unroll
  for (int r = 0; r < 4; ++r) otr[r] = lane_xor<MASK>(ar[r]);
#pragma unroll
  for (int r = 0; r < 4; ++r) oti[r] = lane_xor<MASK>(ai[r]);
#pragma unroll
  for (int r = 0; r < 4; ++r) {
    float nr = cmr*ar[r] - cmi*ai[r] + cor*otr[r] - coi*oti[r];
    float ni = cmr*ai[r] + cmi*ar[r] + cor*oti[r] + coi*otr[r];
    ar[r] = nr; ai[r] = ni;
  }
}

// in-register 2x2 butterfly on one amp pair
__device__ __forceinline__ void bfly(float &a0r, float &a0i, float &a1r, float &a1i,
    float u00r, float u00i, float u01r, float u01i,
    float u10r, float u10i, float u11r, float u11i) {
  float t0r = u00r*a0r - u00i*a0i + u01r*a1r - u01i*a1i;
  float t0i = u00r*a0i + u00i*a0r + u01r*a1i + u01i*a1r;
  float t1r = u10r*a0r - u10i*a0i + u11r*a1r - u11i*a1i;
  float t1i = u10r*a0i + u10i*a0r + u11r*a1i + u11i*a1r;
  a0r=t0r; a0i=t0i; a1r=t1r; a1i=t1i;
}

// complex 2x2 layout: {00r,00i, 01r,01i, 10r,10i, 11r,11i}
__device__ inline void cmul2x2(float* O, const float* A, const float* B) {
  for (int r = 0; r < 2; ++r)
    for (int c = 0; c < 2; ++c) {
      float re = 0.f, im = 0.f;
      for (int j = 0; j < 2; ++j) {
        float ar = A[(r*2+j)*2], ai = A[(r*2+j)*2+1];
        float br = B[(j*2+c)*2], bi = B[(j*2+c)*2+1];
        re += ar*br - ai*bi;
        im += ar*bi + ai*br;
      }
      O[(r*2+c)*2]   = re;
      O[(r*2+c)*2+1] = im;
    }
}
__device__ inline void mk_rx(float* m, float t) {
  float s, c; sincosf(0.5f*t, &s, &c);
  m[0]=c; m[1]=0; m[2]=0; m[3]=-s; m[4]=0; m[5]=-s; m[6]=c; m[7]=0;
}
__device__ inline void mk_ry(float* m, float t) {
  float s, c; sincosf(0.5f*t, &s, &c);
  m[0]=c; m[1]=0; m[2]=-s; m[3]=0; m[4]=s; m[5]=0; m[6]=c; m[7]=0;
}
__device__ inline void mk_rz(float* m, float t) {
  float s, c; sincosf(0.5f*t, &s, &c);
  m[0]=c; m[1]=-s; m[2]=0; m[3]=0; m[4]=0; m[5]=0; m[6]=c; m[7]=s;
}

// one build stage: LDS round-trip applies (perm via idx) + fused gate on amp
// bits 9,8 (K = U ⊗ V, 4x4 complex); then lane gates (bits 7..2); then
// in-register gates (bits 1..0).
__device__ __forceinline__ void build_stage(float (&ar)[4], float (&ai)[4],
    const int (&idx)[4][4], float* __restrict__ sr, float* __restrict__ si,
    int wbase, int lane, int wv, int gbase,
    float O0, float O1, float O2, float O3,
    float O4, float O5, float O6, float O7) {
  // write own amps (padded layout, 16B-aligned base)
#pragma unroll
  for (int r = 0; r < 4; ++r) { sr[wbase + r] = ar[r]; si[wbase + r] = ai[r]; }
  __syncthreads();
  {
    int g0 = gbase, g1 = gbase + 1;
    float U00r=RDL(O0,g0),U00i=RDL(O1,g0),U01r=RDL(O2,g0),U01i=RDL(O3,g0);
    float U10r=RDL(O4,g0),U10i=RDL(O5,g0),U11r=RDL(O6,g0),U11i=RDL(O7,g0);
    float V00r=RDL(O0,g1),V00i=RDL(O1,g1),V01r=RDL(O2,g1),V01i=RDL(O3,g1);
    float V10r=RDL(O4,g1),V10i=RDL(O5,g1),V11r=RDL(O6,g1),V11i=RDL(O7,g1);
    bool w1 = (wv & 2) != 0, w0 = (wv & 1) != 0;
    float uar = w1 ? U10r : U00r, uai = w1 ? U10i : U00i;   // U[W>>1][0]
    float ubr = w1 ? U11r : U01r, ubi = w1 ? U11i : U01i;   // U[W>>1][1]
    float var_ = w0 ? V10r : V00r, vai = w0 ? V10i : V00i;  // V[W&1][0]
    float vbr = w0 ? V11r : V01r, vbi = w0 ? V11i : V01i;   // V[W&1][1]
    float Kr[4], Ki[4];   // K[w] = U[W>>1][w>>1] * V[W&1][w&1]
    Kr[0] = uar*var_ - uai*vai; Ki[0] = uar*vai + uai*var_;
    Kr[1] = uar*vbr - uai*vbi;  Ki[1] = uar*vbi + uai*vbr;
    Kr[2] = ubr*var_ - ubi*vai; Ki[2] = ubr*vai + ubi*var_;
    Kr[3] = ubr*vbr - ubi*vbi;  Ki[3] = ubr*vbi + ubi*vbr;
    float vr[4][4], vi[4][4];
#pragma unroll
    for (int r = 0; r < 4; ++r)
#pragma unroll
      for (int w = 0; w < 4; ++w) { vr[r][w] = sr[idx[r][w]]; vi[r][w] = si[idx[r][w]]; }
#pragma unroll
    for (int r = 0; r < 4; ++r) {
      float nr = 0.f, ni = 0.f;
#pragma unroll
      for (int w = 0; w < 4; ++w) {
        nr += Kr[w]*vr[r][w] - Ki[w]*vi[r][w];
        ni += Kr[w]*vi[r][w] + Ki[w]*vr[r][w];
      }
      ar[r] = nr; ai[r] = ni;
    }
  }
  __syncthreads();
  // lane gates: amp bits 7..2 -> lane masks 32..1 (gates gbase+2 .. gbase+7)
  { int g = gbase + 2; lane_gate4<32>(ar, ai, lane, RDL(O0,g),RDL(O1,g),RDL(O2,g),RDL(O3,g),RDL(O4,g),RDL(O5,g),RDL(O6,g),RDL(O7,g)); }
  { int g = gbase + 3; lane_gate4<16>(ar, ai, lane, RDL(O0,g),RDL(O1,g),RDL(O2,g),RDL(O3,g),RDL(O4,g),RDL(O5,g),RDL(O6,g),RDL(O7,g)); }
  { int g = gbase + 4; lane_gate4< 8>(ar, ai, lane, RDL(O0,g),RDL(O1,g),RDL(O2,g),RDL(O3,g),RDL(O4,g),RDL(O5,g),RDL(O6,g),RDL(O7,g)); }
  { int g = gbase + 5; lane_gate4< 4>(ar, ai, lane, RDL(O0,g),RDL(O1,g),RDL(O2,g),RDL(O3,g),RDL(O4,g),RDL(O5,g),RDL(O6,g),RDL(O7,g)); }
  { int g = gbase + 6; lane_gate4< 2>(ar, ai, lane, RDL(O0,g),RDL(O1,g),RDL(O2,g),RDL(O3,g),RDL(O4,g),RDL(O5,g),RDL(O6,g),RDL(O7,g)); }
  { int g = gbase + 7; lane_gate4< 1>(ar, ai, lane, RDL(O0,g),RDL(O1,g),RDL(O2,g),RDL(O3,g),RDL(O4,g),RDL(O5,g),RDL(O6,g),RDL(O7,g)); }
  // in-register gates: bit1 pairs (0,2),(1,3); bit0 pairs (0,1),(2,3)
  { int g = gbase + 8;
    float u00r=RDL(O0,g),u00i=RDL(O1,g),u01r=RDL(O2,g),u01i=RDL(O3,g);
    float u10r=RDL(O4,g),u10i=RDL(O5,g),u11r=RDL(O6,g),u11i=RDL(O7,g);
    bfly(ar[0],ai[0],ar[2],ai[2], u00r,u00i,u01r,u01i,u10r,u10i,u11r,u11i);
    bfly(ar[1],ai[1],ar[3],ai[3], u00r,u00i,u01r,u01i,u10r,u10i,u11r,u11i);
  }
  { int g = gbase + 9;
    float u00r=RDL(O0,g),u00i=RDL(O1,g),u01r=RDL(O2,g),u01i=RDL(O3,g);
    float u10r=RDL(O4,g),u10i=RDL(O5,g),u11r=RDL(O6,g),u11i=RDL(O7,g);
    bfly(ar[0],ai[0],ar[1],ai[1], u00r,u00i,u01r,u01i,u10r,u10i,u11r,u11i);
    bfly(ar[2],ai[2],ar[3],ai[3], u00r,u00i,u01r,u01i,u10r,u10i,u11r,u11i);
  }
}

// Fused front kernel.
//   blocks [0, 1024):        build_M — block bid handles basis state d = bid.
//                            256 threads; thread owns amps {4*tid + r}.
//   blocks [1024, 1024+2048): row-normalize x (fp32) -> bf16, 4 rows per block.
__global__ __launch_bounds__(256, 4) void fused_front(const float* __restrict__ x,
                                                      const float* __restrict__ w,
                                                      u16* __restrict__ Abf,
                                                      u16* __restrict__ Bmat) {
  const int bid = blockIdx.x;
  const int tid = threadIdx.x;
  const int lane = tid & 63, wv = tid >> 6;

  __shared__ float sr[1152];   // padded: idx + 4*(idx>>5)
  __shared__ float si[1152];

  if (bid >= NBUILD) {
    // ---- normalize path ----
    int row = (bid - NBUILD) * 4 + wv;
    const float* xr = x + (size_t)row * DIMQ;
    float4v v[4];
    float ss = 0.f;
#pragma unroll
    for (int j = 0; j < 4; ++j) {
      v[j] = *(const float4v*)(xr + j*256 + lane*4);
      ss += v[j][0]*v[j][0] + v[j][1]*v[j][1] + v[j][2]*v[j][2] + v[j][3]*v[j][3];
    }
#pragma unroll
    for (int off = 32; off; off >>= 1) ss += __shfl_xor(ss, off, 64);
    float inv = 1.0f / fmaxf(sqrtf(ss), 1e-12f);
    u16* orow = Abf + (size_t)row * DIMQ;
#pragma unroll
    for (int j = 0; j < 4; ++j) {
      u16x4 o;
#pragma unroll
      for (int e = 0; e < 4; ++e) o[e] = f2bf(v[j][e] * inv);
      *(u16x4*)(orow + j*256 + lane*4) = o;
    }
    return;
  }

  // ---- build path ----
  const int d = bid;

  // per-wave: lanes 0..49 compute the 50 fused adjoint gate matrices
  float O0, O1, O2, O3, O4, O5, O6, O7;
  {
    float A[8], B[8], C[8], T8[8], O[8];
    int t = lane;
    if (t < 50) {
      if (t < 10) {
        mk_ry(A, -w[120 + t]);
        mk_rz(B, -w[130 + t]);
        mk_ry(C, -w[140 + t]);
      } else {
        int s = (t - 10) / 10, q = (t - 10) % 10, l = 3 - s;
        mk_rx(A, -w[l*30 + q]);
        mk_ry(B, -w[l*30 + 10 + q]);
        mk_rz(C, -w[l*30 + 20 + q]);
      }
      cmul2x2(T8, A, B);
      cmul2x2(O, T8, C);
    } else {
#pragma unroll
      for (int j = 0; j < 8; ++j) O[j] = 0.f;
    }
    O0=O[0]; O1=O[1]; O2=O[2]; O3=O[3]; O4=O[4]; O5=O[5]; O6=O[6]; O7=O[7];
  }

  // precompute LDS read indices.
  // sigma (adjoint CNOT-ring perm, verified) is GF(2)-linear:
  // sigma(xb ^ r ^ (t<<8)) = sigma(xb) ^ S[r] ^ SW[t]
  int xb = tid * 4;
  int yb = xb;
#pragma unroll
  for (int qq = 0; qq < 9; ++qq) yb ^= ((yb >> (9 - qq)) & 1) << (8 - qq);
  yb ^= (yb & 1) << 9;
  const int S[4]  = {0, 513, 515, 2};      // sigma(0..3)
  const int SW[4] = {0, 1023, 511, 512};   // sigma((0..3)<<8)
  int idxP[4][4], idxI[4][4];              // [r][w], padded
#pragma unroll
  for (int r = 0; r < 4; ++r)
#pragma unroll
    for (int wq = 0; wq < 4; ++wq) {
      int t = wv ^ wq;
      int yP = yb ^ S[r] ^ SW[t];
      idxP[r][wq] = yP + 4 * (yP >> 5);
      int yI = xb ^ r ^ (t << 8);
      idxI[r][wq] = yI + 4 * (yI >> 5);
    }
  int wbase = xb + 4 * (tid >> 3);

  float ar[4], ai[4];
#pragma unroll
  for (int r = 0; r < 4; ++r) {
    ar[r] = (xb + r == d) ? 1.0f : 0.0f;
    ai[r] = 0.0f;
  }

  // stage 0 (identity indices), stages 1..4 (perm indices)
  build_stage(ar, ai, idxI, sr, si, wbase, lane, wv, 0, O0,O1,O2,O3,O4,O5,O6,O7);
#pragma clang loop unroll(disable)
  for (int stage = 1; stage < 5; ++stage)
    build_stage(ar, ai, idxP, sr, si, wbase, lane, wv, stage*10, O0,O1,O2,O3,O4,O5,O6,O7);

  // write row d of M = Re(U) as bf16 (8B per thread, fully coalesced)
  u16x4 o;
#pragma unroll
  for (int r = 0; r < 4; ++r) o[r] = f2bf(ar[r]);
  *(u16x4*)(Bmat + (size_t)d * DIMQ + xb) = o;
}

// C[8192,1024] = A[8192,1024] * B[1024,1024]^T   (bf16 in, fp32 out)
// 128x128 tile, BK=32, 4 waves (2x2 of 64x64), 16x16x32 bf16 MFMA,
// global_load_lds width-16 staging (m97 structure).
__global__ __launch_bounds__(256) void gemm_bt(const u16* __restrict__ A,
                                               const u16* __restrict__ Bm,
                                               float* __restrict__ C) {
  __shared__ u16 As[128*32];
  __shared__ u16 Bs[128*32];
  int t = threadIdx.x, lane = t & 63, wave = t >> 6;
  int bid = blockIdx.x;
  int nid = ((bid & 7) << 6) | (bid >> 3);
  int bm = nid >> 3, bn = nid & 7;
  size_t aBase = (size_t)bm * 128 * KDIM;
  size_t bBase = (size_t)bn * 128 * KDIM;
  int r0 = wave*16 + (lane >> 2);
  int c0 = (lane & 3) * 8;
  int wm = (wave >> 1) * 64, wn = (wave & 1) * 64;
  int la = lane & 15, lk = (lane >> 4) * 8;
  f32x4 acc[4][4];
#pragma unroll
  for (int m = 0; m < 4; ++m)
#pragma unroll
    for (int n = 0; n < 4; ++n) acc[m][n] = (f32x4){0.f, 0.f, 0.f, 0.f};

  for (int k0 = 0; k0 < KDIM; k0 += 32) {
    __syncthreads();
#pragma unroll
    for (int j = 0; j < 2; ++j) {
      __builtin_amdgcn_global_load_lds(
          (const __attribute__((address_space(1))) void*)(A + aBase + (size_t)(j*64 + r0)*KDIM + k0 + c0),
          (__attribute__((address_space(3))) void*)((char*)As + j*4096 + wave*1024), 16, 0, 0);
      __builtin_amdgcn_global_load_lds(
          (const __attribute__((address_space(1))) void*)(Bm + bBase + (size_t)(j*64 + r0)*KDIM + k0 + c0),
          (__attribute__((address_space(3))) void*)((char*)Bs + j*4096 + wave*1024), 16, 0, 0);
    }
    __syncthreads();
    short8 af[4], bf[4];
#pragma unroll
    for (int m = 0; m < 4; ++m) af[m] = *(const short8*)&As[(wm + m*16 + la)*32 + lk];
#pragma unroll
    for (int n = 0; n < 4; ++n) bf[n] = *(const short8*)&Bs[(wn + n*16 + la)*32 + lk];
#pragma unroll
    for (int m = 0; m < 4; ++m)
#pragma unroll
      for (int n = 0; n < 4; ++n)
        acc[m][n] = __builtin_amdgcn_mfma_f32_16x16x32_bf16(af[m], bf[n], acc[m][n], 0, 0, 0);
  }

  int orow0 = bm*128 + wm + (lane >> 4)*4;
  int ocol0 = bn*128 + wn + la;
#pragma unroll
  for (int m = 0; m < 4; ++m)
#pragma unroll
    for (int n = 0; n < 4; ++n)
#pragma unroll
      for (int j = 0; j < 4; ++j)
        C[(size_t)(orow0 + m*16 + j)*NDIM + ocol0 + n*16] = acc[m][n][j];
}

extern "C" void kernel_launch(void* const* d_in, const int* in_sizes, int n_in,
                              void* d_out, int out_size, void* d_ws, size_t ws_size,
                              hipStream_t stream) {
  const float* x = (const float*)d_in[0];
  const float* w = (const float*)d_in[1];
  float* out = (float*)d_out;
  char* ws = (char*)d_ws;
  u16* Bmat = (u16*)(ws + 4096);                             // 2 MB
  u16* Abf  = (u16*)(ws + 4096 + 2*1024*1024);               // 16 MB

  fused_front<<<NBUILD + BATCH/4, 256, 0, stream>>>(x, w, Abf, Bmat);
  gemm_bt<<<(BATCH/128)*(NDIM/128), 256, 0, stream>>>(Abf, Bmat, out);
}